// Round 11
// baseline (49.570 us; speedup 1.0000x reference)
//
#include <hip/hip_runtime.h>

// MorphologicalLayer: ops='co', windows=[51,25] on [16, 8, 262144] f32.
//   y1 = max51(zp(x)); y2 = min51(zp(y1)); y3 = min25(zp(y2)); y4 = max25(zp(y3))
// Wave-independent chunks: each wave owns 1880 outputs; 2048 floats staged in
// a private 8 KiB LDS region (NSLOT=512 -> 32 KiB/block -> 5 blocks/CU,
// 20 waves/CU). All halo exchange is wave-internal LDS (per-wave DS FIFO +
// data deps) -> ZERO __syncthreads. Interior chunks fuse min51∘min25 = min75
// (3 stages); first/last chunk of each row run the exact 4-stage chain with
// per-stage zero clamps.
// Validity chain @NSLOT=512 (locals): stage1(K51,bh<=491) valid <1984;
// stage2(K75,bh<=485) valid <1910; stage3(K25,bh<=498) valid <1886;
// edge chain (51,51,25,25): <1984, <1933, <1909, <1885.
// Claimed locals [2, 1882) -> T_W = 1880. All inside every chain.

#define L_ROW   262144
#define N_ROWS  128          // B*C = 16*8
#define BLOCK   256          // 4 independent waves
#define E       32           // elements per lane
#define EF4     8            // E/4
#define T_W     1880         // claimed outputs per wave chunk (mult of 4)
#define N_CHUNKS 140         // ceil(262144 / 1880); 140 = 35 blocks x 4 waves
#define NSLOT   512          // f4 slots per wave region (2048 floats, 8192 B)

typedef float f32x2 __attribute__((ext_vector_type(2)));

// XOR swizzle at float4 granularity: spreads per-lane 128B-strided accesses
// across all 8 bank-quads. Involution, bijective on mult-of-8 ranges.
__device__ __forceinline__ int swz(int s) { return s ^ ((s >> 3) & 7); }

// Compiler-only memory fence: DS ops from one wave execute in program order
// in HW; this stops the compiler reordering them (per-thread index ranges are
// disjoint, so it otherwise legally could).
#define WFENCE() asm volatile("" ::: "memory")

template<bool MX>
__device__ __forceinline__ float mm(float a, float b) {
  return MX ? fmaxf(a, b) : fminf(a, b);
}

__device__ __forceinline__ void edge_zero(float* r, int goff, int lane, bool edge) {
  if (edge) {
    const int base = goff + lane * E;
#pragma unroll
    for (int i = 0; i < E; ++i)
      if ((unsigned)(base + i) >= (unsigned)L_ROW) r[i] = 0.0f;
  }
}

__device__ __forceinline__ void writeback(const float* r, float4* buf, int b4) {
  WFENCE();   // this stage's halo reads stay above the stores
#pragma unroll
  for (int j = 0; j < EF4; ++j)
    buf[swz(b4 + j)] = make_float4(r[4*j], r[4*j+1], r[4*j+2], r[4*j+3]);
  WFENCE();   // next stage's reads stay below the stores
}

// K in {51, 75}: all windows [i, i+K-1], i in [0,32), straddle the boundary
// at 32. out[i] = mm(S[i], Base&Top prefix at i+K-1). Writes back for
// neighbors. Lanes whose halo reads would exceed the region are clamped
// (K-DEPENDENT bound: max slot read is bh+15+BN); their outputs are garbage
// but lie beyond the claimed range (validity chain in header).
template<int K, bool MX>
__device__ __forceinline__ void stage_big(float* r, float4* buf, int lane,
                                          int goff, bool edge) {
  constexpr int BLEN = K - 33;              // 18 / 42 (== 2 mod 4)
  constexpr int BN   = (BLEN + 2) / 4;      // 5 / 11 base-side f4 slots
  const int b4 = lane * EF4;
  const int bh = min(b4, NSLOT - 16 - BN);  // K=51: 491; K=75: 485

  // Base = mm over halo floats [32 .. K-2], lane-wise accumulators
  float4 v0 = buf[swz(bh + 8)];
  float a0 = v0.x, a1 = v0.y, a2 = v0.z, a3 = v0.w;
#pragma unroll
  for (int j = 1; j < BN - 1; ++j) {
    float4 v = buf[swz(bh + 8 + j)];
    a0 = mm<MX>(a0, v.x); a1 = mm<MX>(a1, v.y);
    a2 = mm<MX>(a2, v.z); a3 = mm<MX>(a3, v.w);
  }
  float4 vl = buf[swz(bh + 8 + BN - 1)];    // 2 base floats + T[0], T[1]
  const float Base = mm<MX>(mm<MX>(mm<MX>(a0, a1), mm<MX>(a2, a3)),
                            mm<MX>(vl.x, vl.y));
  // Top: halo floats [K-1 .. K+30]
  float T[34];
  T[0] = vl.z; T[1] = vl.w;
#pragma unroll
  for (int j = 0; j < 8; ++j) {
    float4 v = buf[swz(bh + 8 + BN + j)];
    T[2+4*j] = v.x; T[3+4*j] = v.y; T[4+4*j] = v.z; T[5+4*j] = v.w;
  }

  // S[i] = mm(r[i..31]) via blocked-8 suffix + cascade (in place)
#pragma unroll
  for (int b = 0; b < 4; ++b)
#pragma unroll
    for (int i = 8*b + 6; i >= 8*b; --i) r[i] = mm<MX>(r[i], r[i+1]);
  const float S2 = r[24];
  const float S1 = mm<MX>(r[16], S2);
  const float S0 = mm<MX>(r[8],  S1);
#pragma unroll
  for (int i = 0;  i < 8;  ++i) r[i] = mm<MX>(r[i], S0);
#pragma unroll
  for (int i = 8;  i < 16; ++i) r[i] = mm<MX>(r[i], S1);
#pragma unroll
  for (int i = 16; i < 24; ++i) r[i] = mm<MX>(r[i], S2);

  // Top prefix within blocks of 8 + head cascade
#pragma unroll
  for (int b = 0; b < 4; ++b)
#pragma unroll
    for (int i = 8*b + 1; i < 8*b + 8; ++i) T[i] = mm<MX>(T[i-1], T[i]);
  const float G0 = mm<MX>(Base, T[7]);
  const float G1 = mm<MX>(G0,   T[15]);
  const float G2 = mm<MX>(G1,   T[23]);

  // out[i] = mm(S[i], head, T[i])
#pragma unroll
  for (int i = 0;  i < 8;  ++i) r[i] = mm<MX>(r[i], mm<MX>(Base, T[i]));
#pragma unroll
  for (int i = 8;  i < 16; ++i) r[i] = mm<MX>(r[i], mm<MX>(G0, T[i]));
#pragma unroll
  for (int i = 16; i < 24; ++i) r[i] = mm<MX>(r[i], mm<MX>(G1, T[i]));
#pragma unroll
  for (int i = 24; i < 32; ++i) r[i] = mm<MX>(r[i], mm<MX>(G2, T[i]));

  edge_zero(r, goff, lane, edge);
  writeback(r, buf, b4);
}

// K = 25: chunk A (i in [0,16)) straddles 16; chunk B (i in [16,32)) straddles 32.
template<bool MX>
__device__ __forceinline__ void stage_25(float* r, float4* buf, int lane,
                                         int goff, bool edge) {
  const int b4 = lane * EF4;
  const int bh = min(b4, NSLOT - 14);       // 498: lane 63 clamped (garbage
                                            // >= 2016, outside claimed range)
  float h[24];                              // halo floats [32..55]
#pragma unroll
  for (int j = 0; j < 6; ++j) {
    float4 v = buf[swz(bh + 8 + j)];        // max slot 498+13 = 511 < 512
    h[4*j] = v.x; h[4*j+1] = v.y; h[4*j+2] = v.z; h[4*j+3] = v.w;
  }

  // t = prefix over raw r[24..31] (before in-place S destroys it)
  float t[8];
  t[0] = r[24];
#pragma unroll
  for (int i = 1; i < 8; ++i) t[i] = mm<MX>(t[i-1], r[24+i]);
  // S_B over r[16..31] (blocked)
#pragma unroll
  for (int i = 30; i >= 24; --i) r[i] = mm<MX>(r[i], r[i+1]);
#pragma unroll
  for (int i = 22; i >= 16; --i) r[i] = mm<MX>(r[i], r[i+1]);
  const float cA = r[16];                   // mm(raw r[16..23])
  const float A3 = r[24];
#pragma unroll
  for (int i = 16; i < 24; ++i) r[i] = mm<MX>(r[i], A3);
  // S_A over r[0..15]
#pragma unroll
  for (int i = 14; i >= 8; --i) r[i] = mm<MX>(r[i], r[i+1]);
#pragma unroll
  for (int i = 6;  i >= 0; --i) r[i] = mm<MX>(r[i], r[i+1]);
  const float A1 = r[8];
#pragma unroll
  for (int i = 0; i < 8; ++i) r[i] = mm<MX>(r[i], A1);
  // halo prefix in blocks of 8
#pragma unroll
  for (int b = 0; b < 3; ++b)
#pragma unroll
    for (int i = 8*b + 1; i < 8*b + 8; ++i) h[i] = mm<MX>(h[i-1], h[i]);
  const float aB  = h[7];                   // mm(halo 32..39)
  const float cA2 = mm<MX>(cA, t[7]);       // mm(own 16..31)
  const float G1  = mm<MX>(aB, h[15]);      // mm(halo 32..47)
  // out[i] = mm(S, head, scan)   windows [i, i+24]
#pragma unroll
  for (int i = 0;  i < 8;  ++i) r[i] = mm<MX>(r[i], mm<MX>(cA,  t[i]));
#pragma unroll
  for (int i = 8;  i < 16; ++i) r[i] = mm<MX>(r[i], mm<MX>(cA2, h[i-8]));
#pragma unroll
  for (int i = 16; i < 24; ++i) r[i] = mm<MX>(r[i], mm<MX>(aB,  h[i-8]));
#pragma unroll
  for (int i = 24; i < 32; ++i) r[i] = mm<MX>(r[i], mm<MX>(G1,  h[i-8]));

  edge_zero(r, goff, lane, edge);
  writeback(r, buf, b4);
}

__global__ __launch_bounds__(BLOCK)
void morph_co_kernel(const float* __restrict__ x, float* __restrict__ out) {
  __shared__ float4 lds4[4 * NSLOT];        // 32768 B -> 5 blocks/CU

  const int w    = threadIdx.x >> 6;
  const int lane = threadIdx.x & 63;
  const int c    = blockIdx.x * 4 + w;      // chunk index within the row
  const int row  = blockIdx.y;

  float4* buf = lds4 + w * NSLOT;           // private per-wave region
  const float* __restrict__ xrow = x   + (size_t)row * L_ROW;
  float* __restrict__       orow = out + (size_t)row * L_ROW;

  const int ob = c * T_W;                   // claimed outputs [ob, ob+T_W)
  const int c0 = ob - 76;                   // buffer float 0 = x[c0]; 4-aligned
  const bool edge = (c == 0) || (c == N_CHUNKS - 1);
  const int b4 = lane * EF4;
  float r[E];

  // ---- staging: global -> private LDS region (swizzled layout)
  if (!edge) {
#pragma unroll
    for (int it = 0; it < 8; ++it) {        // 8*64 = 512 slots exactly
      const int s = it * 64 + lane;
      const float* g = xrow + c0 + 4 * swz(s);     // pre-swizzled source
      __builtin_amdgcn_global_load_lds(
          (const __attribute__((address_space(1))) void*)g,
          (__attribute__((address_space(3))) void*)(&buf[it * 64]), 16, 0, 0);
    }
    asm volatile("s_waitcnt vmcnt(0)" ::: "memory");
  } else {
#pragma unroll
    for (int it = 0; it < 8; ++it) {
      const int s = it * 64 + lane;
      const int g = c0 + 4 * s;
      float4 v;
      v.x = ((unsigned)(g + 0) < (unsigned)L_ROW) ? xrow[g + 0] : 0.0f;
      v.y = ((unsigned)(g + 1) < (unsigned)L_ROW) ? xrow[g + 1] : 0.0f;
      v.z = ((unsigned)(g + 2) < (unsigned)L_ROW) ? xrow[g + 2] : 0.0f;
      v.w = ((unsigned)(g + 3) < (unsigned)L_ROW) ? xrow[g + 3] : 0.0f;
      buf[swz(s)] = v;
    }
    WFENCE();
  }

  // own block -> registers (persists across stages)
#pragma unroll
  for (int j = 0; j < EF4; ++j) {
    float4 v = buf[swz(b4 + j)];
    r[4*j] = v.x; r[4*j+1] = v.y; r[4*j+2] = v.z; r[4*j+3] = v.w;
  }

  if (!edge) {
    // interior: max51 -> min75 (= min25∘min51) -> max25; pads never reached
    stage_big<51, true >(r, buf, lane, 0, false);
    stage_big<75, false>(r, buf, lane, 0, false);
    stage_25 <true >(r, buf, lane, 0, false);
  } else {
    // exact chain with per-stage zero padding (offsets 25/50/62/74)
    stage_big<51, true >(r, buf, lane, c0 + 25, true);
    stage_big<51, false>(r, buf, lane, c0 + 50, true);
    stage_25 <false>(r, buf, lane, c0 + 62, true);
    stage_25 <true >(r, buf, lane, c0 + 74, true);
  }

  // ---- copy-out: buffer float l holds out[ob + l - 2], claimed l in
  // [2, T_W+2). Lane-contiguous LDS reads; 8B-aligned f32x2 global stores.
  // Slot u covers positions 4u-2 .. 4u+1 relative to ob.
  if (!edge) {
#pragma unroll
    for (int it = 0; it < 8; ++it) {
      const int u = it * 64 + lane;
      if (u <= T_W / 4) {                    // 470
        float4 v = buf[swz(u)];
        float* p = orow + ob + 4 * u;
        if (u >= 1)          *reinterpret_cast<f32x2*>(p - 2) = f32x2{v.x, v.y};
        if (u <  T_W / 4)    *reinterpret_cast<f32x2*>(p)     = f32x2{v.z, v.w};
      }
    }
  } else {
    const int hi = min(ob + T_W, L_ROW);
#pragma unroll
    for (int it = 0; it < 8; ++it) {
      const int u = it * 64 + lane;
      if (u <= T_W / 4) {
        float4 v = buf[swz(u)];
        const int p = ob - 2 + 4 * u;
        if (p     >= ob && p     < hi) orow[p]     = v.x;
        if (p + 1 >= ob && p + 1 < hi) orow[p + 1] = v.y;
        if (p + 2 >= ob && p + 2 < hi) orow[p + 2] = v.z;
        if (p + 3 >= ob && p + 3 < hi) orow[p + 3] = v.w;
      }
    }
  }
}

extern "C" void kernel_launch(void* const* d_in, const int* in_sizes, int n_in,
                              void* d_out, int out_size, void* d_ws, size_t ws_size,
                              hipStream_t stream) {
  const float* x = (const float*)d_in[0];
  float* out = (float*)d_out;
  dim3 grid(N_CHUNKS / 4, N_ROWS);          // 35 x 128 blocks, 4 waves each
  morph_co_kernel<<<grid, BLOCK, 0, stream>>>(x, out);
}